// Round 1
// baseline (1521.481 us; speedup 1.0000x reference)
//
#include <hip/hip_runtime.h>

// Encoder DAG-GRU: B=16, S=64, H=1024, C=16
// Strategy: G[b,o,s] = hv_s . gate_w[o,:], M[b,o,s] = hv_s . map_w[o,:]
// computed once per node (state row s never changes after step s).
// Per step t: h_in reduce over s (masked; base term when mask==0),
// then GRU cell (gh matmul + pointwise), storing hv and (next step) G/M row.

#define Hh 1024
#define Sx 64
#define Bx 16
#define Cx 16

__device__ __forceinline__ float sigm(float x) { return 1.0f / (1.0f + __expf(-x)); }
__device__ __forceinline__ float tanhfast(float x) { return 2.0f / (1.0f + __expf(-2.0f * x)) - 1.0f; }

__device__ __forceinline__ float wave_sum(float v) {
    v += __shfl_xor(v, 32, 64);
    v += __shfl_xor(v, 16, 64);
    v += __shfl_xor(v, 8, 64);
    v += __shfl_xor(v, 4, 64);
    v += __shfl_xor(v, 2, 64);
    v += __shfl_xor(v, 1, 64);
    return v;
}

// Kernel A (step t): compute G/M row t-1 from hv_{t-1}, then h_in for step t.
// grid 512, block 256. wave w of block g: o = g*2 + (w>>1), b-half = w&1.
__global__ __launch_bounds__(256) void kA(
    float* __restrict__ G, float* __restrict__ M,
    float* __restrict__ hin, const float* __restrict__ hv,
    const float* __restrict__ dep,
    const float* __restrict__ gate_w, const float* __restrict__ gate_b,
    const float* __restrict__ map_w, const float* __restrict__ map_b,
    int t)
{
    const int wid = threadIdx.x >> 6;
    const int kl = threadIdx.x & 63;
    const int o = blockIdx.x * 2 + (wid >> 1);
    const int b0 = (wid & 1) * 8;

    const float gb = gate_b[o];
    const float mb = map_b[o];
    const float base = sigm(gb) * mb;

    float wgv[16], wmv[16];
    if (t > 0) {
#pragma unroll
        for (int i = 0; i < 16; i++) {
            wgv[i] = gate_w[o * Hh + kl + 64 * i];
            wmv[i] = map_w[o * Hh + kl + 64 * i];
        }
    }

    for (int b = b0; b < b0 + 8; b++) {
        float newG = 0.0f, newM = 0.0f;
        if (t > 0) {
            float pg = 0.0f, pm = 0.0f;
#pragma unroll
            for (int i = 0; i < 16; i++) {
                float h = hv[b * Hh + kl + 64 * i];
                pg += h * wgv[i];
                pm += h * wmv[i];
            }
            newG = wave_sum(pg);
            newM = wave_sum(pm);
            if (kl == 0) {
                G[(b * Hh + o) * Sx + (t - 1)] = newG;
                M[(b * Hh + o) * Sx + (t - 1)] = newM;
            }
        }
        // h_in: lane kl handles s = kl
        float mk = dep[b * Sx * Sx + t * Sx + kl];
        float Gs = G[(b * Hh + o) * Sx + kl];
        float Ms = M[(b * Hh + o) * Sx + kl];
        if (t > 0 && kl == t - 1) { Gs = newG; Ms = newM; }
        float term = (mk != 0.0f) ? (sigm(Gs + gb) * (Ms + mb)) : base;
        term = wave_sum(term);
        if (kl == 0) hin[b * Hh + o] = term;
    }
}

// Kernel B (step t): GRU cell. hv[b,o] from h_in (gh matmul + gi inline).
__global__ __launch_bounds__(256) void kB(
    float* __restrict__ hv, const float* __restrict__ hin,
    const float* __restrict__ ne, const float* __restrict__ w_ih,
    const float* __restrict__ w_hh, const float* __restrict__ b_ih,
    const float* __restrict__ b_hh, int t)
{
    const int wid = threadIdx.x >> 6;
    const int kl = threadIdx.x & 63;
    const int o = blockIdx.x * 2 + (wid >> 1);
    const int b0 = (wid & 1) * 8;

    float wr[16], wz[16], wn[16];
#pragma unroll
    for (int i = 0; i < 16; i++) {
        wr[i] = w_hh[(o) * Hh + kl + 64 * i];
        wz[i] = w_hh[(Hh + o) * Hh + kl + 64 * i];
        wn[i] = w_hh[(2 * Hh + o) * Hh + kl + 64 * i];
    }
    float wir = 0.0f, wiz = 0.0f, win = 0.0f;
    if (kl < Cx) {
        wir = w_ih[o * Cx + kl];
        wiz = w_ih[(Hh + o) * Cx + kl];
        win = w_ih[(2 * Hh + o) * Cx + kl];
    }
    const float bir = b_ih[o], biz = b_ih[Hh + o], bin_ = b_ih[2 * Hh + o];
    const float bhr = b_hh[o], bhz = b_hh[Hh + o], bhn = b_hh[2 * Hh + o];

    for (int b = b0; b < b0 + 8; b++) {
        float pr = 0.0f, pz = 0.0f, pnh = 0.0f;
#pragma unroll
        for (int i = 0; i < 16; i++) {
            float h = hin[b * Hh + kl + 64 * i];
            pr += h * wr[i];
            pz += h * wz[i];
            pnh += h * wn[i];
        }
        float pni = 0.0f;
        if (kl < Cx) {
            float xv = ne[b * Sx * Cx + t * Cx + kl];
            pr += xv * wir;
            pz += xv * wiz;
            pni = xv * win;
        }
        pr = wave_sum(pr);
        pz = wave_sum(pz);
        pnh = wave_sum(pnh);
        pni = wave_sum(pni);
        float r = sigm(pr + bir + bhr);
        float z = sigm(pz + biz + bhz);
        float n = tanhfast(pni + bin_ + r * (pnh + bhn));
        float hprev = hin[b * Hh + o];
        float out = (1.0f - z) * n + z * hprev;
        if (kl == 0) hv[b * Hh + o] = out;
    }
}

// Final: out = [hv | mu | logvar]
__global__ __launch_bounds__(256) void kF(
    float* __restrict__ out, const float* __restrict__ hv,
    const float* __restrict__ w1, const float* __restrict__ b1,
    const float* __restrict__ w2, const float* __restrict__ b2)
{
    const int wid = threadIdx.x >> 6;
    const int kl = threadIdx.x & 63;
    const int o = blockIdx.x * 2 + (wid >> 1);
    const int b0 = (wid & 1) * 8;

    float w1v[16], w2v[16];
#pragma unroll
    for (int i = 0; i < 16; i++) {
        w1v[i] = w1[o * Hh + kl + 64 * i];
        w2v[i] = w2[o * Hh + kl + 64 * i];
    }
    for (int b = b0; b < b0 + 8; b++) {
        float p1 = 0.0f, p2 = 0.0f;
#pragma unroll
        for (int i = 0; i < 16; i++) {
            float h = hv[b * Hh + kl + 64 * i];
            p1 += h * w1v[i];
            p2 += h * w2v[i];
        }
        p1 = wave_sum(p1);
        p2 = wave_sum(p2);
        if (kl == 0) {
            out[b * Hh + o] = hv[b * Hh + o];
            out[Bx * Hh + b * Hh + o] = p1 + b1[o];
            out[2 * Bx * Hh + b * Hh + o] = p2 + b2[o];
        }
    }
}

extern "C" void kernel_launch(void* const* d_in, const int* in_sizes, int n_in,
                              void* d_out, int out_size, void* d_ws, size_t ws_size,
                              hipStream_t stream) {
    const float* dep     = (const float*)d_in[0];
    const float* ne      = (const float*)d_in[1];
    const float* gate_w  = (const float*)d_in[2];
    const float* gate_b  = (const float*)d_in[3];
    const float* map_w   = (const float*)d_in[4];
    const float* map_b   = (const float*)d_in[5];
    const float* w_ih    = (const float*)d_in[6];
    const float* w_hh    = (const float*)d_in[7];
    const float* b_ih    = (const float*)d_in[8];
    const float* b_hh    = (const float*)d_in[9];
    const float* lin11_w = (const float*)d_in[10];
    const float* lin11_b = (const float*)d_in[11];
    const float* lin12_w = (const float*)d_in[12];
    const float* lin12_b = (const float*)d_in[13];

    float* ws  = (float*)d_ws;
    float* G   = ws;                       // [B][H][S] = 1M floats
    float* M   = G + Bx * Hh * Sx;         // 1M floats
    float* hin = M + Bx * Hh * Sx;         // 16K floats
    float* hv  = hin + Bx * Hh;            // 16K floats

    for (int t = 0; t < Sx; t++) {
        kA<<<512, 256, 0, stream>>>(G, M, hin, hv, dep, gate_w, gate_b, map_w, map_b, t);
        kB<<<512, 256, 0, stream>>>(hv, hin, ne, w_ih, w_hh, b_ih, b_hh, t);
    }
    kF<<<512, 256, 0, stream>>>((float*)d_out, hv, lin11_w, lin11_b, lin12_w, lin12_b);
}